// Round 12
// baseline (168.986 us; speedup 1.0000x reference)
//
#include <hip/hip_runtime.h>
#include <math.h>

// ---------------- constants ----------------
#define BIGV      1e9f
#define WARP_PEN  134.4f
#define MASK_INF_C 100000.0f

#define B   8
#define H   192
#define T   400
#define NP  401                  // padded matrix dim (0..400)
#define NPROB 16                 // 2 dirs x 8 batches
#define PSLAB 163712             // padded-diag slab per problem (floats), incl. tail slack
#define SBLOCKS 768              // scalar-loss blocks in fused kernel

// ---------------- workspace layout (float offsets) ----------------
#define SLOT_OFF 16
#define LSP_OFF 160
#define LSQ_OFF (160 + B*T)
#define C1P_OFF (160 + 2*B*T)
#define C1Q_OFF (160 + 3*B*T)
#define DMAT_OFF (160 + 4*B*T)   // 12960 floats, 16B aligned

// Padded diagonal base: every diag starts at a multiple-of-4 float offset.
__device__ __forceinline__ int diag_pbase(int k) {
    if (k <= 400) { int a = k >> 2, b = k & 3; return 4*(a+1)*(2*a+b); }
    int n = k - 401, c = n >> 2, d = n & 3;
    return 81204 + 404*n - 4*(2*c*(c-1) + c*(d+1));
}
__device__ __forceinline__ int i0pad(int k) {
    return (k > 400) ? ((k - 400) & ~3) : 0;
}

// DPP wave_shr:1 — lane i gets src from lane i-1; lane 0 gets `fill`.
__device__ __forceinline__ float wave_shr1(float src, float fill) {
    int r = __builtin_amdgcn_update_dpp(__float_as_int(fill), __float_as_int(src),
                                        0x138 /*wave_shr:1*/, 0xf, 0xf, false);
    return __int_as_float(r);
}

// ---------------- kernel 2: per-(b,t) column sums (4-way h-split) ----------
__global__ __launch_bounds__(256)
void colsum(const float* __restrict__ logs_p, const float* __restrict__ m_p,
            const float* __restrict__ logs_q, const float* __restrict__ m_q,
            float* __restrict__ ws) {
    int b = blockIdx.x / 7;
    int lane = threadIdx.x & 63;
    int hq = threadIdx.x >> 6;                 // 0..3, 48 h each
    int t = (blockIdx.x % 7) * 64 + lane;
    __shared__ float part[4][4][64];
    float lp_s = 0.f, lq_s = 0.f, c1p = 0.f, c1q = 0.f;
    if (t < T) {
        int base = b*H*T + hq*48*T + t;
        const float* LP = logs_p + base;
        const float* MP = m_p   + base;
        const float* LQ = logs_q + base;
        const float* MQ = m_q   + base;
#pragma unroll 4
        for (int h = 0; h < 48; ++h) {
            float lp = LP[h*T], mp = MP[h*T];
            float lq = LQ[h*T], mq = MQ[h*T];
            lp_s += lp;
            lq_s += lq;
            c1p += __expf(-2.f*lp) * mp * mp;
            c1q += __expf(-2.f*lq) * mq * mq;
        }
    }
    part[hq][0][lane] = lp_s;
    part[hq][1][lane] = lq_s;
    part[hq][2][lane] = c1p;
    part[hq][3][lane] = c1q;
    __syncthreads();
    if (hq == 0 && t < T) {
        float a0 = part[0][0][lane] + part[1][0][lane] + part[2][0][lane] + part[3][0][lane];
        float a1 = part[0][1][lane] + part[1][1][lane] + part[2][1][lane] + part[3][1][lane];
        float a2 = part[0][2][lane] + part[1][2][lane] + part[2][2][lane] + part[3][2][lane];
        float a3 = part[0][3][lane] + part[1][3][lane] + part[2][3][lane] + part[3][3][lane];
        ws[LSP_OFF + b*T + t] = a0;
        ws[LSQ_OFF + b*T + t] = a1;
        ws[C1P_OFF + b*T + t] = a2;
        ws[C1Q_OFF + b*T + t] = a3;
    }
}

// ---------------- kernel 3: KL cost matrix (two FP32 dot-GEMMs) ----------------
#define TILE 64
#define KH 32
__global__ __launch_bounds__(256)
void kl_gemm(const float* __restrict__ z_p, const float* __restrict__ m_p,
             const float* __restrict__ logs_p,
             const float* __restrict__ z_q, const float* __restrict__ m_q,
             const float* __restrict__ logs_q,
             const int* __restrict__ p_mask, const int* __restrict__ z_mask,
             float* __restrict__ ws) {
    int prob = blockIdx.y;
    int dir = prob >> 3, b = prob & 7;
    int tp = blockIdx.x / 7, tq = blockIdx.x % 7;
    int p0 = tp * TILE, q0 = tq * TILE;

    const float* lp_arr = dir ? logs_q : logs_p;
    const float* m_arr  = dir ? m_q    : m_p;
    const float* z_arr  = dir ? z_q    : z_p;
    const float* Lp = ws + (dir ? LSQ_OFF : LSP_OFF) + b*T;
    const float* Lq = ws + (dir ? LSP_OFF : LSQ_OFF) + b*T;
    const float* C1 = ws + (dir ? C1Q_OFF : C1P_OFF) + b*T;
    const int* rmask = dir ? z_mask : p_mask;
    const int* cmask = dir ? p_mask : z_mask;

    __shared__ __align__(16) float As [KH][TILE+4];
    __shared__ __align__(16) float AMs[KH][TILE+4];
    __shared__ __align__(16) float Zs [KH][TILE+4];
    __shared__ __align__(16) float Z2s[KH][TILE+4];

    int tid = threadIdx.x;
    int tx = tid & 15, ty = tid >> 4;

    float acc1[4][4] = {{0.f}}, acc2[4][4] = {{0.f}};

    const float* lpB = lp_arr + b*H*T;
    const float* mB  = m_arr  + b*H*T;
    const float* zB  = z_arr  + b*H*T;

    for (int h0 = 0; h0 < H; h0 += KH) {
        for (int e = tid; e < KH*TILE; e += 256) {
            int hh = e >> 6, tt = e & 63;
            int pg = p0 + tt; if (pg > T-1) pg = T-1;
            int qg = q0 + tt; if (qg > T-1) qg = T-1;
            float lp = lpB[(h0+hh)*T + pg];
            float mv = mB [(h0+hh)*T + pg];
            float a  = __expf(-2.f*lp);
            As [hh][tt] = a;
            AMs[hh][tt] = a * mv;
            float zv = zB[(h0+hh)*T + qg];
            Zs [hh][tt] = zv;
            Z2s[hh][tt] = zv * zv;
        }
        __syncthreads();
#pragma unroll 8
        for (int hh = 0; hh < KH; ++hh) {
            const float4 av  = *(const float4*)(&As [hh][ty*4]);
            const float4 amv = *(const float4*)(&AMs[hh][ty*4]);
            const float4 zv  = *(const float4*)(&Zs [hh][tx*4]);
            const float4 z2v = *(const float4*)(&Z2s[hh][tx*4]);
            const float pa[4]  = {av.x, av.y, av.z, av.w};
            const float pam[4] = {amv.x, amv.y, amv.z, amv.w};
            const float qz[4]  = {zv.x, zv.y, zv.z, zv.w};
            const float qz2[4] = {z2v.x, z2v.y, z2v.z, z2v.w};
#pragma unroll
            for (int ii = 0; ii < 4; ++ii)
#pragma unroll
                for (int jj = 0; jj < 4; ++jj) {
                    acc1[ii][jj] = fmaf(pa[ii],  qz2[jj], acc1[ii][jj]);
                    acc2[ii][jj] = fmaf(pam[ii], qz[jj],  acc2[ii][jj]);
                }
        }
        __syncthreads();
    }

    float* Dm = ws + DMAT_OFF + (size_t)prob * PSLAB;
#pragma unroll
    for (int ii = 0; ii < 4; ++ii) {
        int p = p0 + ty*4 + ii;
        if (p > NP-1) continue;
        int pc = p < T ? p : T-1;
        float lpv = Lp[pc];
        float c1v = C1[pc];
        bool pmv = (p < T) && (rmask[b*T + p] != 0);
#pragma unroll
        for (int jj = 0; jj < 4; ++jj) {
            int q = q0 + tx*4 + jj;
            if (q > NP-1) continue;
            int qc = q < T ? q : T-1;
            bool qmv = (q < T) && (cmask[b*T + q] != 0);
            float val = lpv - Lq[qc] - 0.5f*(float)H
                      + 0.5f*(acc1[ii][jj] - 2.f*acc2[ii][jj] + c1v);
            float outv = (pmv != qmv) ? MASK_INF_C : ((!pmv && !qmv) ? 0.f : val);
            int k = p + q;
            Dm[diag_pbase(k) + p - i0pad(k)] = outv;
        }
    }
}

// ---------------- fused kernel: DTW (blocks 0..15) + scalar losses ----------
// DTW: one wave/problem, 8 rows/lane, W-shifted min3 recurrence, DPP lane
// boundary, pinned 16-deep register ring.  NEW: s_setprio(2) — the dtw wave
// is a serial issue-critical chain sharing its CU with ~3 HBM-bound scalar
// blocks; priority arbitration gives it the VALU slots it was losing (T5).
__global__ __launch_bounds__(256)
void fused_dtw_scalar(const float* __restrict__ Dd, float* __restrict__ acc,
                      const float* __restrict__ mel, const float* __restrict__ melh,
                      const float* __restrict__ sg,  const float* __restrict__ se,
                      const float* __restrict__ fr,  const float* __restrict__ ff,
                      const int* __restrict__ pm,    const int* __restrict__ zm) {
    if (blockIdx.x < NPROB) {
        // ---------------- DTW path ----------------
        if (threadIdx.x >= 64) return;
        __builtin_amdgcn_s_setprio(2);   // win VALU arbitration vs scalar waves
        int prob = blockIdx.x;
        int lane = threadIdx.x;
        const float* Dp = Dd + (size_t)prob * PSLAB;
        int woff = lane * 8;

        // X/Y: raw R of diags k-2 / k-1 (ping-pong). Aw: R(k-1) + W.
        float X[8], Y[8], Aw[8];
#pragma unroll
        for (int t = 0; t < 8; ++t) { X[t] = BIGV; Y[t] = BIGV; Aw[t] = BIGV; }
        float upw_prev = (lane == 0) ? WARP_PEN : BIGV;   // makes dg0=0 at k=0, lane 0

        float4 ring[16][2];
#pragma unroll
        for (int d = 0; d < 16; ++d) {
            const float* p = Dp + diag_pbase(d) + woff;
            ring[d][0] = *(const float4*)p;
            ring[d][1] = *(const float4*)(p + 4);
        }

#define DTW_STEP(PHI, XA, KVAL, DO_PF)                                        \
    {                                                                          \
        float upw = wave_shr1(Aw[7], BIGV);                                    \
        float dg0 = upw_prev - WARP_PEN;                                       \
        /* v = min3(d_raw, Aw[t], Aw[t-1]) + D; descending t for in-place */   \
        float v7 = fminf(XA[6], fminf(Aw[7], Aw[6])) + ring[PHI][1].w; XA[7] = v7; \
        float v6 = fminf(XA[5], fminf(Aw[6], Aw[5])) + ring[PHI][1].z; XA[6] = v6; \
        float v5 = fminf(XA[4], fminf(Aw[5], Aw[4])) + ring[PHI][1].y; XA[5] = v5; \
        float v4 = fminf(XA[3], fminf(Aw[4], Aw[3])) + ring[PHI][1].x; XA[4] = v4; \
        float v3 = fminf(XA[2], fminf(Aw[3], Aw[2])) + ring[PHI][0].w; XA[3] = v3; \
        float v2 = fminf(XA[1], fminf(Aw[2], Aw[1])) + ring[PHI][0].z; XA[2] = v2; \
        float v1 = fminf(XA[0], fminf(Aw[1], Aw[0])) + ring[PHI][0].y; XA[1] = v1; \
        float v0 = fminf(dg0,   fminf(Aw[0], upw  )) + ring[PHI][0].x; XA[0] = v0; \
        if (DO_PF) {                                                           \
            int kp = (KVAL) + 16; if (kp > 800) kp = 800;                      \
            int off = __builtin_amdgcn_readfirstlane(                          \
                          diag_pbase(kp) - i0pad(kp));                         \
            const float* p_ = Dp + off + woff;                                 \
            ring[PHI][0] = *(const float4*)p_;                                 \
            ring[PHI][1] = *(const float4*)(p_ + 4);                           \
            __builtin_amdgcn_sched_barrier(0);  /* pin load issue HERE */      \
        }                                                                      \
        Aw[7] = v7 + WARP_PEN; Aw[6] = v6 + WARP_PEN;                          \
        Aw[5] = v5 + WARP_PEN; Aw[4] = v4 + WARP_PEN;                          \
        Aw[3] = v3 + WARP_PEN; Aw[2] = v2 + WARP_PEN;                          \
        Aw[1] = v1 + WARP_PEN; Aw[0] = v0 + WARP_PEN;                          \
        upw_prev = upw;                                                        \
    }

        for (int kb = 0; kb < 800; kb += 16) {
            DTW_STEP( 0, X, kb +  0, 1)
            DTW_STEP( 1, Y, kb +  1, 1)
            DTW_STEP( 2, X, kb +  2, 1)
            DTW_STEP( 3, Y, kb +  3, 1)
            DTW_STEP( 4, X, kb +  4, 1)
            DTW_STEP( 5, Y, kb +  5, 1)
            DTW_STEP( 6, X, kb +  6, 1)
            DTW_STEP( 7, Y, kb +  7, 1)
            DTW_STEP( 8, X, kb +  8, 1)
            DTW_STEP( 9, Y, kb +  9, 1)
            DTW_STEP(10, X, kb + 10, 1)
            DTW_STEP(11, Y, kb + 11, 1)
            DTW_STEP(12, X, kb + 12, 1)
            DTW_STEP(13, Y, kb + 13, 1)
            DTW_STEP(14, X, kb + 14, 1)
            DTW_STEP(15, Y, kb + 15, 1)
        }
        DTW_STEP(0, X, 800, 0)   // final diagonal k=800
#undef DTW_STEP

        __builtin_amdgcn_s_setprio(0);
        // R[400][400]: row 400 = lane 50, slot 0
        if (lane == 50) atomicAdd(&acc[6 + (prob >> 3)], X[0]);
    } else {
        // ---------------- scalar losses path ----------------
        float s0 = 0.f, s1 = 0.f, s2 = 0.f, s3 = 0.f, s4 = 0.f, s5 = 0.f;
        int tid = (blockIdx.x - NPROB) * 256 + threadIdx.x;
        const int stride = SBLOCKS * 256;

        const float4* fr4 = (const float4*)fr;
        const float4* ff4 = (const float4*)ff;
        for (int i = tid; i < 3072000; i += stride) {
            float4 a = fr4[i], b = ff4[i];
            s2 += fabsf(a.x - b.x) + fabsf(a.y - b.y) + fabsf(a.z - b.z) + fabsf(a.w - b.w);
        }
        const float4* m4 = (const float4*)mel;
        const float4* mh4 = (const float4*)melh;
        for (int i = tid; i < 64000; i += stride) {
            float4 a = m4[i], b = mh4[i];
            s3 += fabsf(a.x - b.x) + fabsf(a.y - b.y) + fabsf(a.z - b.z) + fabsf(a.w - b.w);
        }
        const float4* g4 = (const float4*)sg;
        const float4* e4 = (const float4*)se;
        for (int i = tid; i < 4800; i += stride) {
            float4 a = g4[i], b = e4[i];
            float gx = 1.f - a.x, gy = 1.f - a.y, gz = 1.f - a.z, gw = 1.f - a.w;
            s0 += gx*gx + gy*gy + gz*gz + gw*gw;
            float hx = 1.f - b.x, hy = 1.f - b.y, hz = 1.f - b.z, hw = 1.f - b.w;
            s1 += hx*hx + hy*hy + hz*hz + hw*hw;
        }
        for (int i = tid; i < B*T; i += stride) {
            s4 += (float)pm[i];
            s5 += (float)zm[i];
        }
        for (int off = 32; off > 0; off >>= 1) {
            s0 += __shfl_down(s0, off); s1 += __shfl_down(s1, off);
            s2 += __shfl_down(s2, off); s3 += __shfl_down(s3, off);
            s4 += __shfl_down(s4, off); s5 += __shfl_down(s5, off);
        }
        __shared__ float red[4][8];
        int wid = threadIdx.x >> 6;
        if ((threadIdx.x & 63) == 0) {
            red[wid][0] = s0; red[wid][1] = s1; red[wid][2] = s2;
            red[wid][3] = s3; red[wid][4] = s4; red[wid][5] = s5;
        }
        __syncthreads();
        if (threadIdx.x == 0) {
            float t0 = 0.f, t1 = 0.f, t2 = 0.f, t3 = 0.f, t4 = 0.f, t5 = 0.f;
#pragma unroll
            for (int w = 0; w < 4; ++w) {
                t0 += red[w][0]; t1 += red[w][1]; t2 += red[w][2];
                t3 += red[w][3]; t4 += red[w][4]; t5 += red[w][5];
            }
            float* slot = acc + SLOT_OFF + (blockIdx.x & 7) * 16;
            atomicAdd(&slot[0], t0); atomicAdd(&slot[1], t1);
            atomicAdd(&slot[2], t2); atomicAdd(&slot[3], t3);
            atomicAdd(&slot[4], t4); atomicAdd(&slot[5], t5);
        }
    }
}

// ---------------- kernel 5: assemble outputs ----------------
__global__ void finalize(const float* __restrict__ acc,
                         const float* __restrict__ dur,
                         const float* __restrict__ pit,
                         float* __restrict__ out) {
    if (threadIdx.x != 0 || blockIdx.x != 0) return;
    float t[6] = {0.f, 0.f, 0.f, 0.f, 0.f, 0.f};
    for (int s = 0; s < 8; ++s)
        for (int c = 0; c < 6; ++c)
            t[c] += acc[SLOT_OFF + s*16 + c];
    float gen  = t[0] / 3200.f;
    float e2e  = t[1] / 3200.f;
    float fm   = 4.f * t[2] / 409600.f;
    float melv = 45.f * t[3] / 256000.f;
    float d    = dur[0];
    float p    = pit[0];
    float kl   = acc[6] / t[4];
    float klf  = acc[7] / t[5];
    out[0] = gen; out[1] = e2e; out[2] = fm; out[3] = melv;
    out[4] = d;   out[5] = p;   out[6] = kl; out[7] = klf;
    out[8] = gen + e2e + fm + melv + d + p + kl + klf;
}

// ---------------- launch ----------------
extern "C" void kernel_launch(void* const* d_in, const int* in_sizes, int n_in,
                              void* d_out, int out_size, void* d_ws, size_t ws_size,
                              hipStream_t stream) {
    const float* mel    = (const float*)d_in[0];
    const float* melh   = (const float*)d_in[1];
    const float* sg     = (const float*)d_in[2];
    const float* se     = (const float*)d_in[3];
    const float* fr     = (const float*)d_in[4];
    const float* ff     = (const float*)d_in[5];
    const float* dur    = (const float*)d_in[6];
    const float* pit    = (const float*)d_in[7];
    const float* z_p    = (const float*)d_in[8];
    const float* m_p    = (const float*)d_in[9];
    const float* logs_p = (const float*)d_in[10];
    const float* z_q    = (const float*)d_in[11];
    const float* m_q    = (const float*)d_in[12];
    const float* logs_q = (const float*)d_in[13];
    const int*   p_mask = (const int*)d_in[14];
    const int*   z_mask = (const int*)d_in[15];
    float* ws  = (float*)d_ws;
    float* out = (float*)d_out;

    hipMemsetAsync(ws, 0, 160 * sizeof(float), stream);
    colsum<<<B*7, 256, 0, stream>>>(logs_p, m_p, logs_q, m_q, ws);
    kl_gemm<<<dim3(49, NPROB), 256, 0, stream>>>(z_p, m_p, logs_p, z_q, m_q, logs_q,
                                                 p_mask, z_mask, ws);
    fused_dtw_scalar<<<NPROB + SBLOCKS, 256, 0, stream>>>(ws + DMAT_OFF, ws,
                                                          mel, melh, sg, se, fr, ff,
                                                          p_mask, z_mask);
    finalize<<<1, 64, 0, stream>>>(ws, dur, pit, out);
}

// Round 14
// 149.081 us; speedup vs baseline: 1.1335x; 1.1335x over previous
//
#include <hip/hip_runtime.h>
#include <math.h>

// ---------------- constants ----------------
#define BIGV      1e9f
#define WARP_PEN  134.4f
#define MASK_INF_C 100000.0f

#define B   8
#define H   192
#define T   400
#define NP  401                  // padded matrix dim (0..400)
#define NPROB 16                 // 2 dirs x 8 batches
#define NTIL 51                  // ceil(401/8) tiles per dim
#define TSLAB (NTIL*NTIL*64)     // 166464 floats per problem (tile-major D)
#define SBLOCKS 768              // scalar-loss blocks in fused kernel

typedef float f32x4 __attribute__((ext_vector_type(4)));

// ---------------- workspace layout (float offsets) ----------------
#define SLOT_OFF 16
#define LSP_OFF 160
#define LSQ_OFF (160 + B*T)
#define C1P_OFF (160 + 2*B*T)
#define C1Q_OFF (160 + 3*B*T)
#define DMAT_OFF (160 + 4*B*T)   // 12960 floats, 16B aligned

// DPP wave_shr:1 — lane i gets src from lane i-1; lane 0 gets `fill`.
__device__ __forceinline__ float wave_shr1(float src, float fill) {
    int r = __builtin_amdgcn_update_dpp(__float_as_int(fill), __float_as_int(src),
                                        0x138 /*wave_shr:1*/, 0xf, 0xf, false);
    return __int_as_float(r);
}

// ---------------- kernel 2: per-(b,t) column sums (4-way h-split) ----------
__global__ __launch_bounds__(256)
void colsum(const float* __restrict__ logs_p, const float* __restrict__ m_p,
            const float* __restrict__ logs_q, const float* __restrict__ m_q,
            float* __restrict__ ws) {
    int b = blockIdx.x / 7;
    int lane = threadIdx.x & 63;
    int hq = threadIdx.x >> 6;                 // 0..3, 48 h each
    int t = (blockIdx.x % 7) * 64 + lane;
    __shared__ float part[4][4][64];
    float lp_s = 0.f, lq_s = 0.f, c1p = 0.f, c1q = 0.f;
    if (t < T) {
        int base = b*H*T + hq*48*T + t;
        const float* LP = logs_p + base;
        const float* MP = m_p   + base;
        const float* LQ = logs_q + base;
        const float* MQ = m_q   + base;
#pragma unroll 4
        for (int h = 0; h < 48; ++h) {
            float lp = LP[h*T], mp = MP[h*T];
            float lq = LQ[h*T], mq = MQ[h*T];
            lp_s += lp;
            lq_s += lq;
            c1p += __expf(-2.f*lp) * mp * mp;
            c1q += __expf(-2.f*lq) * mq * mq;
        }
    }
    part[hq][0][lane] = lp_s;
    part[hq][1][lane] = lq_s;
    part[hq][2][lane] = c1p;
    part[hq][3][lane] = c1q;
    __syncthreads();
    if (hq == 0 && t < T) {
        float a0 = part[0][0][lane] + part[1][0][lane] + part[2][0][lane] + part[3][0][lane];
        float a1 = part[0][1][lane] + part[1][1][lane] + part[2][1][lane] + part[3][1][lane];
        float a2 = part[0][2][lane] + part[1][2][lane] + part[2][2][lane] + part[3][2][lane];
        float a3 = part[0][3][lane] + part[1][3][lane] + part[2][3][lane] + part[3][3][lane];
        ws[LSP_OFF + b*T + t] = a0;
        ws[LSQ_OFF + b*T + t] = a1;
        ws[C1P_OFF + b*T + t] = a2;
        ws[C1Q_OFF + b*T + t] = a3;
    }
}

// ---------------- kernel 3: KL cost matrix (two FP32 dot-GEMMs) ----------------
#define TILE 64
#define KH 32
__global__ __launch_bounds__(256)
void kl_gemm(const float* __restrict__ z_p, const float* __restrict__ m_p,
             const float* __restrict__ logs_p,
             const float* __restrict__ z_q, const float* __restrict__ m_q,
             const float* __restrict__ logs_q,
             const int* __restrict__ p_mask, const int* __restrict__ z_mask,
             float* __restrict__ ws) {
    int prob = blockIdx.y;
    int dir = prob >> 3, b = prob & 7;
    int tp = blockIdx.x / 7, tq = blockIdx.x % 7;
    int p0 = tp * TILE, q0 = tq * TILE;

    const float* lp_arr = dir ? logs_q : logs_p;
    const float* m_arr  = dir ? m_q    : m_p;
    const float* z_arr  = dir ? z_q    : z_p;
    const float* Lp = ws + (dir ? LSQ_OFF : LSP_OFF) + b*T;
    const float* Lq = ws + (dir ? LSP_OFF : LSQ_OFF) + b*T;
    const float* C1 = ws + (dir ? C1Q_OFF : C1P_OFF) + b*T;
    const int* rmask = dir ? z_mask : p_mask;
    const int* cmask = dir ? p_mask : z_mask;

    __shared__ __align__(16) float As [KH][TILE+4];
    __shared__ __align__(16) float AMs[KH][TILE+4];
    __shared__ __align__(16) float Zs [KH][TILE+4];
    __shared__ __align__(16) float Z2s[KH][TILE+4];

    int tid = threadIdx.x;
    int tx = tid & 15, ty = tid >> 4;

    float acc1[4][4] = {{0.f}}, acc2[4][4] = {{0.f}};

    const float* lpB = lp_arr + b*H*T;
    const float* mB  = m_arr  + b*H*T;
    const float* zB  = z_arr  + b*H*T;

    for (int h0 = 0; h0 < H; h0 += KH) {
        for (int e = tid; e < KH*TILE; e += 256) {
            int hh = e >> 6, tt = e & 63;
            int pg = p0 + tt; if (pg > T-1) pg = T-1;
            int qg = q0 + tt; if (qg > T-1) qg = T-1;
            float lp = lpB[(h0+hh)*T + pg];
            float mv = mB [(h0+hh)*T + pg];
            float a  = __expf(-2.f*lp);
            As [hh][tt] = a;
            AMs[hh][tt] = a * mv;
            float zv = zB[(h0+hh)*T + qg];
            Zs [hh][tt] = zv;
            Z2s[hh][tt] = zv * zv;
        }
        __syncthreads();
#pragma unroll 8
        for (int hh = 0; hh < KH; ++hh) {
            const float4 av  = *(const float4*)(&As [hh][ty*4]);
            const float4 amv = *(const float4*)(&AMs[hh][ty*4]);
            const float4 zv  = *(const float4*)(&Zs [hh][tx*4]);
            const float4 z2v = *(const float4*)(&Z2s[hh][tx*4]);
            const float pa[4]  = {av.x, av.y, av.z, av.w};
            const float pam[4] = {amv.x, amv.y, amv.z, amv.w};
            const float qz[4]  = {zv.x, zv.y, zv.z, zv.w};
            const float qz2[4] = {z2v.x, z2v.y, z2v.z, z2v.w};
#pragma unroll
            for (int ii = 0; ii < 4; ++ii)
#pragma unroll
                for (int jj = 0; jj < 4; ++jj) {
                    acc1[ii][jj] = fmaf(pa[ii],  qz2[jj], acc1[ii][jj]);
                    acc2[ii][jj] = fmaf(pam[ii], qz[jj],  acc2[ii][jj]);
                }
        }
        __syncthreads();
    }

    // epilogue: kl value + pad/mask, TILE-MAJOR write:
    // cell (p,q) -> [(p>>3)*51 + (q>>3)]*64 + (p&7)*8 + (q&7)
    float* Dm = ws + DMAT_OFF + (size_t)prob * TSLAB;
#pragma unroll
    for (int ii = 0; ii < 4; ++ii) {
        int p = p0 + ty*4 + ii;
        if (p > NP-1) continue;
        int pc = p < T ? p : T-1;
        float lpv = Lp[pc];
        float c1v = C1[pc];
        bool pmv = (p < T) && (rmask[b*T + p] != 0);
#pragma unroll
        for (int jj = 0; jj < 4; ++jj) {
            int q = q0 + tx*4 + jj;
            if (q > NP-1) continue;
            int qc = q < T ? q : T-1;
            bool qmv = (q < T) && (cmask[b*T + q] != 0);
            float val = lpv - Lq[qc] - 0.5f*(float)H
                      + 0.5f*(acc1[ii][jj] - 2.f*acc2[ii][jj] + c1v);
            float outv = (pmv != qmv) ? MASK_INF_C : ((!pmv && !qmv) ? 0.f : val);
            int off = ((p >> 3) * NTIL + (q >> 3)) * 64 + (p & 7) * 8 + (q & 7);
            Dm[off] = outv;
        }
    }
}

// ---------------- fused kernel: DTW (blocks 0..15) + scalar losses ----------
// DTW restructured as an 8x8 TILE wavefront: lane I owns tile-row I; 101
// sequential tile-steps (vs 801 cell-steps). Per step each lane computes 64
// cells (~560cy compute) while the next D-tile loads into the other buffer —
// compute >> latency, so plain double-buffering hides memory. Boundary
// exchange: 9 DPP wave_shr (bottom row + 2-step-old corner from lane I-1).
// Out-of-band tiles (J<0 / J>50 / lanes>50) compute on in-bounds garbage that
// provably never feeds valid cells (DP flows to increasing i,j only).
__global__ __launch_bounds__(256)
void fused_dtw_scalar(const float* __restrict__ Dd, float* __restrict__ acc,
                      const float* __restrict__ mel, const float* __restrict__ melh,
                      const float* __restrict__ sg,  const float* __restrict__ se,
                      const float* __restrict__ fr,  const float* __restrict__ ff,
                      const int* __restrict__ pm,    const int* __restrict__ zm) {
    if (blockIdx.x < NPROB) {
        // ---------------- DTW tile-wavefront path ----------------
        if (threadIdx.x >= 64) return;
        int prob = blockIdx.x;
        int lane = threadIdx.x;
        int Ieff = lane < (NTIL-1) ? lane : (NTIL-1);   // clamp for addressing
        const float* tbase = Dd + (size_t)prob * TSLAB + Ieff * ((NTIL-1) * 64);
        // tile (I, J=s-I) offset = (I*51 + s - I)*64 = I*3200 + s*64

        float botp[8], rightp[8], prow[8];
        float brold = BIGV, v00 = BIGV;
#pragma unroll
        for (int t = 0; t < 8; ++t) { botp[t] = BIGV; rightp[t] = BIGV; }

        f32x4 bufA[16], bufB[16];
#pragma unroll
        for (int t = 0; t < 16; ++t) bufA[t] = *(const f32x4*)(tbase + t * 4);

#define TILE_STEP(CUR, NXT, SVAL, DO_LOAD)                                    \
    {                                                                          \
        const int s_ = (SVAL);                                                 \
        /* boundary exchange from lane I-1 (lockstep, in-register) */          \
        _Pragma("unroll")                                                      \
        for (int c = 0; c < 8; ++c) prow[c] = wave_shr1(botp[c], BIGV);        \
        float corner = wave_shr1(brold, BIGV);                                 \
        bool jz = (s_ == lane);            /* J == 0 */                        \
        if (jz) corner = (lane == 0) ? 0.f : BIGV;                             \
        if (DO_LOAD) {                                                         \
            const float* np_ = tbase + (s_ + 1) * 64;                          \
            _Pragma("unroll")                                                  \
            for (int t = 0; t < 16; ++t) NXT[t] = *(const f32x4*)(np_ + t*4);  \
            __builtin_amdgcn_sched_barrier(0);  /* keep loads before compute */\
        }                                                                      \
        float brnew = botp[7];                                                 \
        float prevR = BIGV;                                                    \
        _Pragma("unroll")                                                      \
        for (int r = 0; r < 8; ++r) {                                          \
            float left = jz ? BIGV : rightp[r];                                \
            float diag = (r == 0) ? corner : (jz ? BIGV : prevR);              \
            prevR = rightp[r];                                                 \
            _Pragma("unroll")                                                  \
            for (int c = 0; c < 8; ++c) {                                      \
                float up = prow[c];                                            \
                float dv = CUR[r*2 + (c>>2)][c & 3];                           \
                float v = fminf(diag, fminf(up, left) + WARP_PEN) + dv;        \
                if (r == 0 && c == 0) v00 = v;                                 \
                diag = up;                                                     \
                left = v;                                                      \
                prow[c] = v;                                                   \
            }                                                                  \
            rightp[r] = prow[7];                                               \
        }                                                                      \
        _Pragma("unroll")                                                      \
        for (int c = 0; c < 8; ++c) botp[c] = prow[c];                         \
        brold = brnew;                                                         \
    }

        for (int sb = 0; sb < 100; sb += 2) {
            TILE_STEP(bufA, bufB, sb,     1)
            TILE_STEP(bufB, bufA, sb + 1, 1)
        }
        TILE_STEP(bufA, bufB, 100, 0)   // final tile-diagonal
#undef TILE_STEP

        // R[400][400] = tile(50,50) cell (0,0), computed at s=100 by lane 50
        if (lane == NTIL-1) atomicAdd(&acc[6 + (prob >> 3)], v00);
    } else {
        // ---------------- scalar losses path ----------------
        float s0 = 0.f, s1 = 0.f, s2 = 0.f, s3 = 0.f, s4 = 0.f, s5 = 0.f;
        int tid = (blockIdx.x - NPROB) * 256 + threadIdx.x;
        const int stride = SBLOCKS * 256;

        const float4* fr4 = (const float4*)fr;
        const float4* ff4 = (const float4*)ff;
        for (int i = tid; i < 3072000; i += stride) {
            float4 a = fr4[i], b = ff4[i];
            s2 += fabsf(a.x - b.x) + fabsf(a.y - b.y) + fabsf(a.z - b.z) + fabsf(a.w - b.w);
        }
        const float4* m4 = (const float4*)mel;
        const float4* mh4 = (const float4*)melh;
        for (int i = tid; i < 64000; i += stride) {
            float4 a = m4[i], b = mh4[i];
            s3 += fabsf(a.x - b.x) + fabsf(a.y - b.y) + fabsf(a.z - b.z) + fabsf(a.w - b.w);
        }
        const float4* g4 = (const float4*)sg;
        const float4* e4 = (const float4*)se;
        for (int i = tid; i < 4800; i += stride) {
            float4 a = g4[i], b = e4[i];
            float gx = 1.f - a.x, gy = 1.f - a.y, gz = 1.f - a.z, gw = 1.f - a.w;
            s0 += gx*gx + gy*gy + gz*gz + gw*gw;
            float hx = 1.f - b.x, hy = 1.f - b.y, hz = 1.f - b.z, hw = 1.f - b.w;
            s1 += hx*hx + hy*hy + hz*hz + hw*hw;
        }
        for (int i = tid; i < B*T; i += stride) {
            s4 += (float)pm[i];
            s5 += (float)zm[i];
        }
        for (int off = 32; off > 0; off >>= 1) {
            s0 += __shfl_down(s0, off); s1 += __shfl_down(s1, off);
            s2 += __shfl_down(s2, off); s3 += __shfl_down(s3, off);
            s4 += __shfl_down(s4, off); s5 += __shfl_down(s5, off);
        }
        __shared__ float red[4][8];
        int wid = threadIdx.x >> 6;
        if ((threadIdx.x & 63) == 0) {
            red[wid][0] = s0; red[wid][1] = s1; red[wid][2] = s2;
            red[wid][3] = s3; red[wid][4] = s4; red[wid][5] = s5;
        }
        __syncthreads();
        if (threadIdx.x == 0) {
            float t0 = 0.f, t1 = 0.f, t2 = 0.f, t3 = 0.f, t4 = 0.f, t5 = 0.f;
#pragma unroll
            for (int w = 0; w < 4; ++w) {
                t0 += red[w][0]; t1 += red[w][1]; t2 += red[w][2];
                t3 += red[w][3]; t4 += red[w][4]; t5 += red[w][5];
            }
            float* slot = acc + SLOT_OFF + (blockIdx.x & 7) * 16;
            atomicAdd(&slot[0], t0); atomicAdd(&slot[1], t1);
            atomicAdd(&slot[2], t2); atomicAdd(&slot[3], t3);
            atomicAdd(&slot[4], t4); atomicAdd(&slot[5], t5);
        }
    }
}

// ---------------- kernel 5: assemble outputs ----------------
__global__ void finalize(const float* __restrict__ acc,
                         const float* __restrict__ dur,
                         const float* __restrict__ pit,
                         float* __restrict__ out) {
    if (threadIdx.x != 0 || blockIdx.x != 0) return;
    float t[6] = {0.f, 0.f, 0.f, 0.f, 0.f, 0.f};
    for (int s = 0; s < 8; ++s)
        for (int c = 0; c < 6; ++c)
            t[c] += acc[SLOT_OFF + s*16 + c];
    float gen  = t[0] / 3200.f;
    float e2e  = t[1] / 3200.f;
    float fm   = 4.f * t[2] / 409600.f;
    float melv = 45.f * t[3] / 256000.f;
    float d    = dur[0];
    float p    = pit[0];
    float kl   = acc[6] / t[4];
    float klf  = acc[7] / t[5];
    out[0] = gen; out[1] = e2e; out[2] = fm; out[3] = melv;
    out[4] = d;   out[5] = p;   out[6] = kl; out[7] = klf;
    out[8] = gen + e2e + fm + melv + d + p + kl + klf;
}

// ---------------- launch ----------------
extern "C" void kernel_launch(void* const* d_in, const int* in_sizes, int n_in,
                              void* d_out, int out_size, void* d_ws, size_t ws_size,
                              hipStream_t stream) {
    const float* mel    = (const float*)d_in[0];
    const float* melh   = (const float*)d_in[1];
    const float* sg     = (const float*)d_in[2];
    const float* se     = (const float*)d_in[3];
    const float* fr     = (const float*)d_in[4];
    const float* ff     = (const float*)d_in[5];
    const float* dur    = (const float*)d_in[6];
    const float* pit    = (const float*)d_in[7];
    const float* z_p    = (const float*)d_in[8];
    const float* m_p    = (const float*)d_in[9];
    const float* logs_p = (const float*)d_in[10];
    const float* z_q    = (const float*)d_in[11];
    const float* m_q    = (const float*)d_in[12];
    const float* logs_q = (const float*)d_in[13];
    const int*   p_mask = (const int*)d_in[14];
    const int*   z_mask = (const int*)d_in[15];
    float* ws  = (float*)d_ws;
    float* out = (float*)d_out;

    hipMemsetAsync(ws, 0, 160 * sizeof(float), stream);
    colsum<<<B*7, 256, 0, stream>>>(logs_p, m_p, logs_q, m_q, ws);
    kl_gemm<<<dim3(49, NPROB), 256, 0, stream>>>(z_p, m_p, logs_p, z_q, m_q, logs_q,
                                                 p_mask, z_mask, ws);
    fused_dtw_scalar<<<NPROB + SBLOCKS, 256, 0, stream>>>(ws + DMAT_OFF, ws,
                                                          mel, melh, sg, se, fr, ff,
                                                          p_mask, z_mask);
    finalize<<<1, 64, 0, stream>>>(ws, dur, pit, out);
}

// Round 15
// 142.348 us; speedup vs baseline: 1.1871x; 1.0473x over previous
//
#include <hip/hip_runtime.h>
#include <math.h>

// ---------------- constants ----------------
#define BIGV      1e9f
#define WARP_PEN  134.4f
#define MASK_INF_C 100000.0f

#define B   8
#define H   192
#define T   400
#define NP  401                  // padded matrix dim (0..400)
#define NPROB 16                 // 2 dirs x 8 batches
#define NTIL 51                  // ceil(401/8) tiles per dim
#define TSLAB (NTIL*NTIL*64)     // 166464 floats per problem (tile-major D)
#define SBLOCKS 768              // scalar-loss blocks in fused kernel

typedef float f32x4 __attribute__((ext_vector_type(4)));

// ---------------- workspace layout (float offsets) ----------------
#define SLOT_OFF 16
#define LSP_OFF 160
#define LSQ_OFF (160 + B*T)
#define C1P_OFF (160 + 2*B*T)
#define C1Q_OFF (160 + 3*B*T)
#define DMAT_OFF (160 + 4*B*T)   // 12960 floats, 16B aligned

// DPP wave_shr:1 — lane i gets src from lane i-1; lane 0 gets `fill`.
__device__ __forceinline__ float wave_shr1(float src, float fill) {
    int r = __builtin_amdgcn_update_dpp(__float_as_int(fill), __float_as_int(src),
                                        0x138 /*wave_shr:1*/, 0xf, 0xf, false);
    return __int_as_float(r);
}

// ---------------- kernel 2: per-(b,t) column sums (4-way h-split) ----------
__global__ __launch_bounds__(256)
void colsum(const float* __restrict__ logs_p, const float* __restrict__ m_p,
            const float* __restrict__ logs_q, const float* __restrict__ m_q,
            float* __restrict__ ws) {
    int b = blockIdx.x / 7;
    int lane = threadIdx.x & 63;
    int hq = threadIdx.x >> 6;                 // 0..3, 48 h each
    int t = (blockIdx.x % 7) * 64 + lane;
    __shared__ float part[4][4][64];
    float lp_s = 0.f, lq_s = 0.f, c1p = 0.f, c1q = 0.f;
    if (t < T) {
        int base = b*H*T + hq*48*T + t;
        const float* LP = logs_p + base;
        const float* MP = m_p   + base;
        const float* LQ = logs_q + base;
        const float* MQ = m_q   + base;
#pragma unroll 4
        for (int h = 0; h < 48; ++h) {
            float lp = LP[h*T], mp = MP[h*T];
            float lq = LQ[h*T], mq = MQ[h*T];
            lp_s += lp;
            lq_s += lq;
            c1p += __expf(-2.f*lp) * mp * mp;
            c1q += __expf(-2.f*lq) * mq * mq;
        }
    }
    part[hq][0][lane] = lp_s;
    part[hq][1][lane] = lq_s;
    part[hq][2][lane] = c1p;
    part[hq][3][lane] = c1q;
    __syncthreads();
    if (hq == 0 && t < T) {
        float a0 = part[0][0][lane] + part[1][0][lane] + part[2][0][lane] + part[3][0][lane];
        float a1 = part[0][1][lane] + part[1][1][lane] + part[2][1][lane] + part[3][1][lane];
        float a2 = part[0][2][lane] + part[1][2][lane] + part[2][2][lane] + part[3][2][lane];
        float a3 = part[0][3][lane] + part[1][3][lane] + part[2][3][lane] + part[3][3][lane];
        ws[LSP_OFF + b*T + t] = a0;
        ws[LSQ_OFF + b*T + t] = a1;
        ws[C1P_OFF + b*T + t] = a2;
        ws[C1Q_OFF + b*T + t] = a3;
    }
}

// ---------------- kernel 3: KL cost matrix (two FP32 dot-GEMMs) ----------------
#define TILE 64
#define KH 32
__global__ __launch_bounds__(256)
void kl_gemm(const float* __restrict__ z_p, const float* __restrict__ m_p,
             const float* __restrict__ logs_p,
             const float* __restrict__ z_q, const float* __restrict__ m_q,
             const float* __restrict__ logs_q,
             const int* __restrict__ p_mask, const int* __restrict__ z_mask,
             float* __restrict__ ws) {
    int prob = blockIdx.y;
    int dir = prob >> 3, b = prob & 7;
    int tp = blockIdx.x / 7, tq = blockIdx.x % 7;
    int p0 = tp * TILE, q0 = tq * TILE;

    const float* lp_arr = dir ? logs_q : logs_p;
    const float* m_arr  = dir ? m_q    : m_p;
    const float* z_arr  = dir ? z_q    : z_p;
    const float* Lp = ws + (dir ? LSQ_OFF : LSP_OFF) + b*T;
    const float* Lq = ws + (dir ? LSP_OFF : LSQ_OFF) + b*T;
    const float* C1 = ws + (dir ? C1Q_OFF : C1P_OFF) + b*T;
    const int* rmask = dir ? z_mask : p_mask;
    const int* cmask = dir ? p_mask : z_mask;

    __shared__ __align__(16) float As [KH][TILE+4];
    __shared__ __align__(16) float AMs[KH][TILE+4];
    __shared__ __align__(16) float Zs [KH][TILE+4];
    __shared__ __align__(16) float Z2s[KH][TILE+4];

    int tid = threadIdx.x;
    int tx = tid & 15, ty = tid >> 4;

    float acc1[4][4] = {{0.f}}, acc2[4][4] = {{0.f}};

    const float* lpB = lp_arr + b*H*T;
    const float* mB  = m_arr  + b*H*T;
    const float* zB  = z_arr  + b*H*T;

    for (int h0 = 0; h0 < H; h0 += KH) {
        for (int e = tid; e < KH*TILE; e += 256) {
            int hh = e >> 6, tt = e & 63;
            int pg = p0 + tt; if (pg > T-1) pg = T-1;
            int qg = q0 + tt; if (qg > T-1) qg = T-1;
            float lp = lpB[(h0+hh)*T + pg];
            float mv = mB [(h0+hh)*T + pg];
            float a  = __expf(-2.f*lp);
            As [hh][tt] = a;
            AMs[hh][tt] = a * mv;
            float zv = zB[(h0+hh)*T + qg];
            Zs [hh][tt] = zv;
            Z2s[hh][tt] = zv * zv;
        }
        __syncthreads();
#pragma unroll 8
        for (int hh = 0; hh < KH; ++hh) {
            const float4 av  = *(const float4*)(&As [hh][ty*4]);
            const float4 amv = *(const float4*)(&AMs[hh][ty*4]);
            const float4 zv  = *(const float4*)(&Zs [hh][tx*4]);
            const float4 z2v = *(const float4*)(&Z2s[hh][tx*4]);
            const float pa[4]  = {av.x, av.y, av.z, av.w};
            const float pam[4] = {amv.x, amv.y, amv.z, amv.w};
            const float qz[4]  = {zv.x, zv.y, zv.z, zv.w};
            const float qz2[4] = {z2v.x, z2v.y, z2v.z, z2v.w};
#pragma unroll
            for (int ii = 0; ii < 4; ++ii)
#pragma unroll
                for (int jj = 0; jj < 4; ++jj) {
                    acc1[ii][jj] = fmaf(pa[ii],  qz2[jj], acc1[ii][jj]);
                    acc2[ii][jj] = fmaf(pam[ii], qz[jj],  acc2[ii][jj]);
                }
        }
        __syncthreads();
    }

    // epilogue: kl value + pad/mask, TILE-MAJOR write:
    // cell (p,q) -> [(p>>3)*51 + (q>>3)]*64 + (p&7)*8 + (q&7)
    float* Dm = ws + DMAT_OFF + (size_t)prob * TSLAB;
#pragma unroll
    for (int ii = 0; ii < 4; ++ii) {
        int p = p0 + ty*4 + ii;
        if (p > NP-1) continue;
        int pc = p < T ? p : T-1;
        float lpv = Lp[pc];
        float c1v = C1[pc];
        bool pmv = (p < T) && (rmask[b*T + p] != 0);
#pragma unroll
        for (int jj = 0; jj < 4; ++jj) {
            int q = q0 + tx*4 + jj;
            if (q > NP-1) continue;
            int qc = q < T ? q : T-1;
            bool qmv = (q < T) && (cmask[b*T + q] != 0);
            float val = lpv - Lq[qc] - 0.5f*(float)H
                      + 0.5f*(acc1[ii][jj] - 2.f*acc2[ii][jj] + c1v);
            float outv = (pmv != qmv) ? MASK_INF_C : ((!pmv && !qmv) ? 0.f : val);
            int off = ((p >> 3) * NTIL + (q >> 3)) * 64 + (p & 7) * 8 + (q & 7);
            Dm[off] = outv;
        }
    }
}

// ---------------- fused kernel: DTW (blocks 0..15) + scalar losses ----------
// 8x8 tile wavefront, 101 steps. launch_bounds(256,1) gives the RA headroom
// to keep BOTH tile buffers (128 VGPR) live -> true double-buffer (R14's
// VGPR=80 proved the buffers were spilled/serialized). Cell update in
// min3 form: v = min3(diag_raw, upW, leftW) + dv (3 VALU, 12cy chain).
__global__ __launch_bounds__(256, 1)
void fused_dtw_scalar(const float* __restrict__ Dd, float* __restrict__ acc,
                      const float* __restrict__ mel, const float* __restrict__ melh,
                      const float* __restrict__ sg,  const float* __restrict__ se,
                      const float* __restrict__ fr,  const float* __restrict__ ff,
                      const int* __restrict__ pm,    const int* __restrict__ zm) {
    if (blockIdx.x < NPROB) {
        // ---------------- DTW tile-wavefront path ----------------
        if (threadIdx.x >= 64) return;
        int prob = blockIdx.x;
        int lane = threadIdx.x;
        int Ieff = lane < (NTIL-1) ? lane : (NTIL-1);   // clamp for addressing
        const float* tbase = Dd + (size_t)prob * TSLAB + Ieff * ((NTIL-1) * 64);
        // tile (I, J=s-I) offset = (I*51 + s - I)*64 = I*3200 + s*64

        // persistent per-lane state:
        // brow/browW: bottom-row raw / +W (becomes up-row after DPP)
        // rightraw/rightW: this lane's tile col-7 raw / +W (left inputs next J)
        float brow[8], browW[8], rightraw[8], rightW[8];
        float brold = BIGV, v00 = BIGV;
#pragma unroll
        for (int t = 0; t < 8; ++t) {
            brow[t] = BIGV; browW[t] = BIGV; rightraw[t] = BIGV; rightW[t] = BIGV;
        }

        f32x4 bufA[16], bufB[16];
#pragma unroll
        for (int t = 0; t < 16; ++t) bufA[t] = *(const f32x4*)(tbase + t * 4);

#define TILE_STEP(CUR, NXT, SVAL, DO_LOAD)                                    \
    {                                                                          \
        const int s_ = (SVAL);                                                 \
        bool jz = (s_ == lane);            /* J == 0 */                        \
        float brnew = brow[7];                                                 \
        /* up-row from lane I-1 (raw + W-shifted), corner from 2 steps ago */  \
        _Pragma("unroll")                                                      \
        for (int c = 0; c < 8; ++c) {                                          \
            brow[c] = wave_shr1(brow[c], BIGV);                                \
            browW[c] = brow[c] + WARP_PEN;                                     \
        }                                                                      \
        float corner = wave_shr1(brold, BIGV);                                 \
        if (jz) corner = (lane == 0) ? 0.f : BIGV;                             \
        if (DO_LOAD) {                                                         \
            const float* np_ = tbase + (s_ + 1) * 64;                          \
            _Pragma("unroll")                                                  \
            for (int t = 0; t < 16; ++t) NXT[t] = *(const f32x4*)(np_ + t*4);  \
            __builtin_amdgcn_sched_barrier(0);  /* loads stay before compute */\
        }                                                                      \
        float dprev = corner;                                                  \
        _Pragma("unroll")                                                      \
        for (int r = 0; r < 8; ++r) {                                          \
            float leftW = jz ? BIGV : rightW[r];                               \
            float dnextrow = jz ? BIGV : rightraw[r];  /* diag for row r+1 */  \
            float diag = dprev;                                                \
            _Pragma("unroll")                                                  \
            for (int c = 0; c < 8; ++c) {                                      \
                float dv = CUR[r*2 + (c>>2)][c & 3];                           \
                float v = fminf(fminf(diag, browW[c]), leftW) + dv;            \
                if (r == 0 && c == 0) v00 = v;                                 \
                float t_ = brow[c];     /* old (r-1,c) = diag for (r,c+1) */   \
                brow[c] = v;                                                   \
                float vW = v + WARP_PEN;                                       \
                browW[c] = vW;                                                 \
                leftW = vW;                                                    \
                diag = t_;                                                     \
            }                                                                  \
            rightraw[r] = brow[7];                                             \
            rightW[r]   = browW[7];                                            \
            dprev = dnextrow;                                                  \
        }                                                                      \
        brold = brnew;                                                         \
    }

        for (int sb = 0; sb < 100; sb += 2) {
            TILE_STEP(bufA, bufB, sb,     1)
            TILE_STEP(bufB, bufA, sb + 1, 1)
        }
        TILE_STEP(bufA, bufB, 100, 0)   // final tile-diagonal
#undef TILE_STEP

        // R[400][400] = tile(50,50) cell (0,0), computed at s=100 by lane 50
        if (lane == NTIL-1) atomicAdd(&acc[6 + (prob >> 3)], v00);
    } else {
        // ---------------- scalar losses path ----------------
        float s0 = 0.f, s1 = 0.f, s2 = 0.f, s3 = 0.f, s4 = 0.f, s5 = 0.f;
        int tid = (blockIdx.x - NPROB) * 256 + threadIdx.x;
        const int stride = SBLOCKS * 256;

        const float4* fr4 = (const float4*)fr;
        const float4* ff4 = (const float4*)ff;
        for (int i = tid; i < 3072000; i += stride) {
            float4 a = fr4[i], b = ff4[i];
            s2 += fabsf(a.x - b.x) + fabsf(a.y - b.y) + fabsf(a.z - b.z) + fabsf(a.w - b.w);
        }
        const float4* m4 = (const float4*)mel;
        const float4* mh4 = (const float4*)melh;
        for (int i = tid; i < 64000; i += stride) {
            float4 a = m4[i], b = mh4[i];
            s3 += fabsf(a.x - b.x) + fabsf(a.y - b.y) + fabsf(a.z - b.z) + fabsf(a.w - b.w);
        }
        const float4* g4 = (const float4*)sg;
        const float4* e4 = (const float4*)se;
        for (int i = tid; i < 4800; i += stride) {
            float4 a = g4[i], b = e4[i];
            float gx = 1.f - a.x, gy = 1.f - a.y, gz = 1.f - a.z, gw = 1.f - a.w;
            s0 += gx*gx + gy*gy + gz*gz + gw*gw;
            float hx = 1.f - b.x, hy = 1.f - b.y, hz = 1.f - b.z, hw = 1.f - b.w;
            s1 += hx*hx + hy*hy + hz*hz + hw*hw;
        }
        for (int i = tid; i < B*T; i += stride) {
            s4 += (float)pm[i];
            s5 += (float)zm[i];
        }
        for (int off = 32; off > 0; off >>= 1) {
            s0 += __shfl_down(s0, off); s1 += __shfl_down(s1, off);
            s2 += __shfl_down(s2, off); s3 += __shfl_down(s3, off);
            s4 += __shfl_down(s4, off); s5 += __shfl_down(s5, off);
        }
        __shared__ float red[4][8];
        int wid = threadIdx.x >> 6;
        if ((threadIdx.x & 63) == 0) {
            red[wid][0] = s0; red[wid][1] = s1; red[wid][2] = s2;
            red[wid][3] = s3; red[wid][4] = s4; red[wid][5] = s5;
        }
        __syncthreads();
        if (threadIdx.x == 0) {
            float t0 = 0.f, t1 = 0.f, t2 = 0.f, t3 = 0.f, t4 = 0.f, t5 = 0.f;
#pragma unroll
            for (int w = 0; w < 4; ++w) {
                t0 += red[w][0]; t1 += red[w][1]; t2 += red[w][2];
                t3 += red[w][3]; t4 += red[w][4]; t5 += red[w][5];
            }
            float* slot = acc + SLOT_OFF + (blockIdx.x & 7) * 16;
            atomicAdd(&slot[0], t0); atomicAdd(&slot[1], t1);
            atomicAdd(&slot[2], t2); atomicAdd(&slot[3], t3);
            atomicAdd(&slot[4], t4); atomicAdd(&slot[5], t5);
        }
    }
}

// ---------------- kernel 5: assemble outputs ----------------
__global__ void finalize(const float* __restrict__ acc,
                         const float* __restrict__ dur,
                         const float* __restrict__ pit,
                         float* __restrict__ out) {
    if (threadIdx.x != 0 || blockIdx.x != 0) return;
    float t[6] = {0.f, 0.f, 0.f, 0.f, 0.f, 0.f};
    for (int s = 0; s < 8; ++s)
        for (int c = 0; c < 6; ++c)
            t[c] += acc[SLOT_OFF + s*16 + c];
    float gen  = t[0] / 3200.f;
    float e2e  = t[1] / 3200.f;
    float fm   = 4.f * t[2] / 409600.f;
    float melv = 45.f * t[3] / 256000.f;
    float d    = dur[0];
    float p    = pit[0];
    float kl   = acc[6] / t[4];
    float klf  = acc[7] / t[5];
    out[0] = gen; out[1] = e2e; out[2] = fm; out[3] = melv;
    out[4] = d;   out[5] = p;   out[6] = kl; out[7] = klf;
    out[8] = gen + e2e + fm + melv + d + p + kl + klf;
}

// ---------------- launch ----------------
extern "C" void kernel_launch(void* const* d_in, const int* in_sizes, int n_in,
                              void* d_out, int out_size, void* d_ws, size_t ws_size,
                              hipStream_t stream) {
    const float* mel    = (const float*)d_in[0];
    const float* melh   = (const float*)d_in[1];
    const float* sg     = (const float*)d_in[2];
    const float* se     = (const float*)d_in[3];
    const float* fr     = (const float*)d_in[4];
    const float* ff     = (const float*)d_in[5];
    const float* dur    = (const float*)d_in[6];
    const float* pit    = (const float*)d_in[7];
    const float* z_p    = (const float*)d_in[8];
    const float* m_p    = (const float*)d_in[9];
    const float* logs_p = (const float*)d_in[10];
    const float* z_q    = (const float*)d_in[11];
    const float* m_q    = (const float*)d_in[12];
    const float* logs_q = (const float*)d_in[13];
    const int*   p_mask = (const int*)d_in[14];
    const int*   z_mask = (const int*)d_in[15];
    float* ws  = (float*)d_ws;
    float* out = (float*)d_out;

    hipMemsetAsync(ws, 0, 160 * sizeof(float), stream);
    colsum<<<B*7, 256, 0, stream>>>(logs_p, m_p, logs_q, m_q, ws);
    kl_gemm<<<dim3(49, NPROB), 256, 0, stream>>>(z_p, m_p, logs_p, z_q, m_q, logs_q,
                                                 p_mask, z_mask, ws);
    fused_dtw_scalar<<<NPROB + SBLOCKS, 256, 0, stream>>>(ws + DMAT_OFF, ws,
                                                          mel, melh, sg, se, fr, ff,
                                                          p_mask, z_mask);
    finalize<<<1, 64, 0, stream>>>(ws, dur, pit, out);
}